// Round 6
// baseline (475.366 us; speedup 1.0000x reference)
//
#include <hip/hip_runtime.h>
#include <hip/hip_bf16.h>

// Problem constants (fixed by reference setup_inputs).
#define T_TOTAL 2048
#define BATCH   128
#define NIN     256
#define NOUT    128

// Reverse-scan formulation (see R3):
//   rtrace[t] = out[t] + 0.5*rtrace[t+1];  dw[o,i] = sum_{t,b} rtrace[t,b,o]*in[t,b,i]
//
// R5 established the sequential HBM->LDS DMA stream (global_load_lds w=16,
// linear LDS == global layout, counted-vmcnt 2-deep pipeline): stdp ~125 us
// (~3 TB/s), best yet but still ~2x the 64 us floor. Compute per group is
// ~600 cyc vs ~4700 cyc group time -> the wait is vmcnt delivery. With
// grid=256 (1 block/CU) all 8 waves share barrier phases: demand is bursty
// and only 48 KiB/CU is ever in flight.
//
// ROUND 6 CHANGE (single variable): TC 256->128 => grid 512 = 2 blocks/CU
// (launch_bounds(512,4), LDS 2x48=96 KiB/CU). The two resident blocks are
// mutually desynchronized: one block's vmcnt/barrier phase is covered by the
// other's DMA issue + compute, keeping the VMEM queue continuously fed
// (96 KiB/CU in flight). Main loop body byte-identical to R5.
#define TC      128                 // timesteps per block
#define BC      4                   // batches per block
#define WARM    32                  // reverse warm-up steps (0.5^32 ~ 2e-10)
#define G       4                   // timesteps per MFMA K-group (K = G*BC = 16)
#define NTC     (T_TOTAL / TC)      // 16
#define NBC     (BATCH / BC)        // 32
#define NBLOCKS (NTC * NBC)         // 512  (2 blocks/CU)
#define NG      (TC / G)            // 32 K-groups per block

#define OUT_ELEMS (NOUT * NIN)      // 32768

static_assert(NG % 2 == 0, "2-stage pipeline needs even group count");

typedef __attribute__((ext_vector_type(8)))  __bf16 bf16x8;
typedef __attribute__((ext_vector_type(2)))  __bf16 bf16x2;
typedef __attribute__((ext_vector_type(16))) float  f32x16;

// packed f32x2 -> bf16x2 (v_cvt_pk_bf16_f32 on gfx950, RTNE; exact for {0,1})
static __device__ __forceinline__ unsigned pack_bf16(float a, float b) {
    bf16x2 v = { (__bf16)a, (__bf16)b };
    union { bf16x2 v; unsigned u; } c; c.v = v; return c.u;
}

static __device__ __forceinline__ bf16x8 frag_from4(unsigned d0, unsigned d1,
                                                    unsigned d2, unsigned d3) {
    union { unsigned u[4]; bf16x8 v; } c;
    c.u[0] = d0; c.u[1] = d1; c.u[2] = d2; c.u[3] = d3; return c.v;
}

// Direct global->LDS DMA, 16 B/lane. LDS dest = wave-uniform base + lane*16
// (m104); size must be a literal.
static __device__ __forceinline__ void gload16(const float* g, void* l) {
    __builtin_amdgcn_global_load_lds(
        (const __attribute__((address_space(1))) void*)g,
        (__attribute__((address_space(3))) void*)l,
        16, 0, 0);
}

// Wave w = (mt = w&3, nh = w>>2): output tile o in [mt*32,+32), i in
// [nh*128,+128). Lane (l31, kh): A-frag elem j: (q=j&3, b=2kh+(j>=4)) ->
// lane scans rtrace for (o=mt*32+l31, b0+2kh / b0+2kh+1) in registers.
// B-frag elem j, tile tn: in[tg+(j&3)][b0+2kh+(j>=4)][(nh*4+tn)*32+l31].
__global__ __launch_bounds__(512, 4)
void stdp_main(const float* __restrict__ in, const float* __restrict__ outs,
               float* __restrict__ dst, int nslots, int use_atomic)
{
    // fp32 staging, layout == global layout (linear, required by DMA):
    // in_lds [s][q(4)][b(4)][i(256)]  = 16 KiB/stage
    // out_lds[s][q(4)][b(4)][o(128)]  =  8 KiB/stage
    __shared__ float in_lds [2][G * BC * NIN];
    __shared__ float out_lds[2][G * BC * NOUT];

    const int tid = threadIdx.x;
    const int bc  = blockIdx.x % NBC;
    const int tc  = blockIdx.x / NBC;
    const int b0  = bc * BC;
    const int t0  = tc * TC;

    const int lane = tid & 63;
    const int wv   = tid >> 6;           // 8 waves
    const int mt   = wv & 3;             // o-tile (rows mt*32..+31)
    const int nh   = wv >> 2;            // i-half (cols nh*128..+127)
    const int l31  = lane & 31;
    const int kh   = lane >> 5;          // selects b-pair {2kh, 2kh+1}

    const size_t OST = (size_t)BATCH * NOUT;

    // ---- reverse warm-up (scalar loads; ~32 MB chip-wide, mostly L2-absorbed)
    const float* __restrict__ outW = outs + (size_t)(b0 + 2 * kh) * NOUT + mt * 32 + l31;
    float rtrA = 0.f, rtrB = 0.f;
    if (tc < NTC - 1) {
        for (int tb = t0 + TC + WARM; tb > t0 + TC; tb -= 8) {
            float vA[8], vB[8];
#pragma unroll
            for (int u = 0; u < 8; ++u) {
                vA[u] = outW[(size_t)(tb - 1 - u) * OST];
                vB[u] = outW[(size_t)(tb - 1 - u) * OST + NOUT];
            }
#pragma unroll
            for (int u = 0; u < 8; ++u) {
                rtrA = vA[u] + 0.5f * rtrA;
                rtrB = vB[u] + 0.5f * rtrB;
            }
        }
    }

    f32x16 acc[4];
#pragma unroll
    for (int j = 0; j < 4; ++j) acc[j] = (f32x16)(0.f);

    // ---- DMA decomposition (derived so LDS-linear == global-contiguous):
    // in chunk 16 KiB = 16 x (t,b)-rows of 1 KiB; wave wv, instr r covers
    //   (q = 2r + (wv>>2), b = wv&3), lanes span i = lane*4..+3.
    // out chunk 8 KiB = 8 pieces; wave wv covers (q = wv>>1,
    //   b = 2*(wv&1) + (lane>>5)), lanes span o = (lane&31)*4..+3.
    const float* inS  = in   + (size_t)(b0 + (wv & 3)) * NIN  + lane * 4;
    const float* outS = outs + (size_t)(b0 + 2 * (wv & 1) + kh) * NOUT + l31 * 4;
    const int    tin  = wv >> 2;         // + 2r
    const int    tot  = wv >> 1;
    char* inL  = (char*)&in_lds[0][0]  + wv * 1024;
    char* outL = (char*)&out_lds[0][0] + wv * 1024;

    auto dma_group = [&](int s, int g) {    // 3 DMA instrs / thread / group
        const int tg = t0 + g * G;
        gload16(inS  + (size_t)(tg + tin)     * (BATCH * NIN),  inL + s * 16384);
        gload16(inS  + (size_t)(tg + tin + 2) * (BATCH * NIN),  inL + s * 16384 + 8192);
        gload16(outS + (size_t)(tg + tot)     * (BATCH * NOUT), outL + s * 8192);
    };

    // LDS frag-read bases (byte offsets; q/be/tn/s fold into ds imm offsets).
    // B: byte = s*16384 + q*4096 + be*1024 + [kh*2048 + nh*512 + tn*128 + l31*4]
    // A: byte = s*8192  + q*2048 + be*512  + [kh*1024 + mt*128 + l31*4]
    const char* ilb = (const char*)&in_lds [0][0] + kh * 2048 + nh * 512 + l31 * 4;
    const char* olb = (const char*)&out_lds[0][0] + kh * 1024 + mt * 128 + l31 * 4;

    auto body = [&](int s, int g, int vm) {
        // stage-s DMAs are the 3 oldest outstanding; 3 newer may stay in flight
        if (vm) asm volatile("s_waitcnt vmcnt(3)" ::: "memory");
        else    asm volatile("s_waitcnt vmcnt(0)" ::: "memory");
        __builtin_amdgcn_s_barrier();            // all waves' stage-s data landed
        __builtin_amdgcn_sched_barrier(0);       // no ds_read hoists above

        // A side: read out-spike rows, reverse-scan rtrace (descending t)
        float vA[4], vB[4];
#pragma unroll
        for (int q = 0; q < 4; ++q) {
            vA[q] = *(const float*)(olb + s * 8192 + q * 2048);        // b = 2kh
            vB[q] = *(const float*)(olb + s * 8192 + q * 2048 + 512);  // b = 2kh+1
        }
        float aA[4], aB[4];
#pragma unroll
        for (int q = 3; q >= 0; --q) {
            rtrA = vA[q] + 0.5f * rtrA; aA[q] = rtrA;
            rtrB = vB[q] + 0.5f * rtrB; aB[q] = rtrB;
        }
        const bf16x8 a = frag_from4(pack_bf16(aA[0], aA[1]), pack_bf16(aA[2], aA[3]),
                                    pack_bf16(aB[0], aB[1]), pack_bf16(aB[2], aB[3]));
        bf16x8 bfr[4];
#pragma unroll
        for (int tn = 0; tn < 4; ++tn) {
            float p[8];
#pragma unroll
            for (int be = 0; be < 2; ++be)
#pragma unroll
                for (int q = 0; q < 4; ++q)
                    p[be * 4 + q] = *(const float*)
                        (ilb + s * 16384 + q * 4096 + be * 1024 + tn * 128);
            bfr[tn] = frag_from4(pack_bf16(p[0], p[1]), pack_bf16(p[2], p[3]),
                                 pack_bf16(p[4], p[5]), pack_bf16(p[6], p[7]));
        }
#pragma unroll
        for (int tn = 0; tn < 4; ++tn)
            acc[tn] = __builtin_amdgcn_mfma_f32_32x32x16_bf16(a, bfr[tn], acc[tn], 0, 0, 0);

        asm volatile("s_waitcnt lgkmcnt(0)" ::: "memory");  // my stage-s reads done
        __builtin_amdgcn_s_barrier();                       // everyone's reads done
        __builtin_amdgcn_sched_barrier(0);                  // DMA stays below barrier
        if (g >= 2) dma_group(s, g - 2);                    // refill stage s
    };

    // prologue: 6 DMAs outstanding, then steady-state 2-deep pipeline
    dma_group(1, NG - 1);
    dma_group(0, NG - 2);
    for (int gg = NG - 1; gg >= 3; gg -= 2) {
        body(1, gg, 1);
        body(0, gg - 1, 1);
    }
    body(1, 1, 1);
    body(0, 0, 0);   // last group: drain fully

    // ---- epilogue: D[row, col] -> dw[o = mt*32+row, i = (nh*4+j)*32+col] ----
    float* base = dst + (size_t)(use_atomic ? (blockIdx.x % nslots) : blockIdx.x) * OUT_ELEMS;
#pragma unroll
    for (int j = 0; j < 4; ++j) {
        const int icol = (nh * 4 + j) * 32 + l31;
#pragma unroll
        for (int r = 0; r < 16; ++r) {
            const int row = (r & 3) + 8 * (r >> 2) + 4 * kh;
            const int o   = mt * 32 + row;
            const float v = acc[j][r];
            if (use_atomic) atomicAdd(&base[o * NIN + icol], v);
            else            base[o * NIN + icol] = v;
        }
    }
}

__global__ void zero_kernel(float* p, int n) {
    int i = blockIdx.x * blockDim.x + threadIdx.x;
    if (i < n) p[i] = 0.f;
}

__global__ __launch_bounds__(256)
void reduce_kernel(const float* __restrict__ ws, float* __restrict__ outp, int nslots) {
    const int idx = blockIdx.x * 256 + threadIdx.x;
    float s = 0.f;
    int k = 0;
    for (; k + 16 <= nslots; k += 16) {
        float v[16];
#pragma unroll
        for (int u = 0; u < 16; ++u) v[u] = ws[(size_t)(k + u) * OUT_ELEMS + idx];
#pragma unroll
        for (int u = 0; u < 16; ++u) s += v[u];
    }
    for (; k < nslots; ++k) s += ws[(size_t)k * OUT_ELEMS + idx];
    outp[idx] = s;
}

extern "C" void kernel_launch(void* const* d_in, const int* in_sizes, int n_in,
                              void* d_out, int out_size, void* d_ws, size_t ws_size,
                              hipStream_t stream) {
    const float* in   = (const float*)d_in[0];
    const float* outs = (const float*)d_in[1];
    float* out = (float*)d_out;
    float* ws  = (float*)d_ws;

    const size_t slot_bytes = (size_t)OUT_ELEMS * sizeof(float);

    if (ws_size >= (size_t)NBLOCKS * slot_bytes) {
        // plain per-block partials + reduce (preferred; atomics cost ~+30 us, R4)
        stdp_main<<<NBLOCKS, 512, 0, stream>>>(in, outs, ws, NBLOCKS, 0);
        reduce_kernel<<<OUT_ELEMS / 256, 256, 0, stream>>>(ws, out, NBLOCKS);
    } else if (ws_size >= 16 * slot_bytes) {
        zero_kernel<<<(16 * OUT_ELEMS + 255) / 256, 256, 0, stream>>>(ws, 16 * OUT_ELEMS);
        stdp_main<<<NBLOCKS, 512, 0, stream>>>(in, outs, ws, 16, 1);
        reduce_kernel<<<OUT_ELEMS / 256, 256, 0, stream>>>(ws, out, 16);
    } else {
        zero_kernel<<<(OUT_ELEMS + 255) / 256, 256, 0, stream>>>(out, OUT_ELEMS);
        stdp_main<<<NBLOCKS, 512, 0, stream>>>(in, outs, out, 1, 1);
    }
}

// Round 7
// 451.034 us; speedup vs baseline: 1.0539x; 1.0539x over previous
//
#include <hip/hip_runtime.h>
#include <hip/hip_bf16.h>

// Problem constants (fixed by reference setup_inputs).
#define T_TOTAL 2048
#define BATCH   128
#define NIN     256
#define NOUT    128

// Reverse-scan formulation (see R3):
//   rtrace[t] = out[t] + 0.5*rtrace[t+1];  dw[o,i] = sum_{t,b} rtrace[t,b,o]*in[t,b,i]
//
// R5 (1 blk/CU, sequential HBM->LDS DMA, 2-deep): stdp ~138 us (~2.6 TB/s).
// R6 (2 blk/CU): REGRESSED to 178 us -> concurrency via a second
// barrier-synced block interferes; depth must come from within the block.
//
// ROUND 7 CHANGE (single variable vs R5): pipeline depth 2 -> 4.
// 4 LDS stages x 24 KiB = 96 KiB (dynamic LDS; plain-HIP >64 KiB workgroups
// are proven on gfx950 - m201 uses 128 KiB). Steady-state wait is vmcnt(9):
// the 3 younger groups' 9 DMAs stay in flight across barriers, 96 KiB/CU
// outstanding. Tail drains 9 -> 6 -> 3 -> 0. Everything else (grid=256,
// TC=256, DMA decomposition, fragment reads, barrier structure, epilogue,
// reduce) byte-identical to R5.
#define TC      256                 // timesteps per block
#define BC      4                   // batches per block
#define WARM    32                  // reverse warm-up steps (0.5^32 ~ 2e-10)
#define G       4                   // timesteps per MFMA K-group (K = G*BC = 16)
#define NTC     (T_TOTAL / TC)      // 8
#define NBC     (BATCH / BC)        // 32
#define NBLOCKS (NTC * NBC)         // 256  (1 block/CU)
#define NG      (TC / G)            // 64 K-groups per block

#define OUT_ELEMS (NOUT * NIN)      // 32768
#define LDS_BYTES (4 * (16384 + 8192))   // 96 KiB: 4 stages x (16K in + 8K out)

static_assert(NG % 4 == 0, "4-stage pipeline needs NG % 4 == 0");

typedef __attribute__((ext_vector_type(8)))  __bf16 bf16x8;
typedef __attribute__((ext_vector_type(2)))  __bf16 bf16x2;
typedef __attribute__((ext_vector_type(16))) float  f32x16;

// packed f32x2 -> bf16x2 (v_cvt_pk_bf16_f32 on gfx950, RTNE; exact for {0,1})
static __device__ __forceinline__ unsigned pack_bf16(float a, float b) {
    bf16x2 v = { (__bf16)a, (__bf16)b };
    union { bf16x2 v; unsigned u; } c; c.v = v; return c.u;
}

static __device__ __forceinline__ bf16x8 frag_from4(unsigned d0, unsigned d1,
                                                    unsigned d2, unsigned d3) {
    union { unsigned u[4]; bf16x8 v; } c;
    c.u[0] = d0; c.u[1] = d1; c.u[2] = d2; c.u[3] = d3; return c.v;
}

// Direct global->LDS DMA, 16 B/lane. LDS dest = wave-uniform base + lane*16
// (m104); size must be a literal.
static __device__ __forceinline__ void gload16(const float* g, void* l) {
    __builtin_amdgcn_global_load_lds(
        (const __attribute__((address_space(1))) void*)g,
        (__attribute__((address_space(3))) void*)l,
        16, 0, 0);
}

// Wave w = (mt = w&3, nh = w>>2): output tile o in [mt*32,+32), i in
// [nh*128,+128). Lane (l31, kh): A-frag elem j: (q=j&3, b=2kh+(j>=4)) ->
// lane scans rtrace for (o=mt*32+l31, b0+2kh / b0+2kh+1) in registers.
// B-frag elem j, tile tn: in[tg+(j&3)][b0+2kh+(j>=4)][(nh*4+tn)*32+l31].
__global__ __launch_bounds__(512, 2)
void stdp_main(const float* __restrict__ in, const float* __restrict__ outs,
               float* __restrict__ dst, int nslots, int use_atomic)
{
    // Dynamic LDS, layout == global layout (linear, required by DMA):
    //   in_lds : 4 stages x [q(4)][b(4)][i(256)] fp32 = 4 x 16 KiB at offset 0
    //   out_lds: 4 stages x [q(4)][b(4)][o(128)] fp32 = 4 x  8 KiB at 65536
    extern __shared__ char smem[];
    char* inBase  = smem;
    char* outBase = smem + 4 * 16384;

    const int tid = threadIdx.x;
    const int bc  = blockIdx.x % NBC;
    const int tc  = blockIdx.x / NBC;
    const int b0  = bc * BC;
    const int t0  = tc * TC;

    const int lane = tid & 63;
    const int wv   = tid >> 6;           // 8 waves
    const int mt   = wv & 3;             // o-tile (rows mt*32..+31)
    const int nh   = wv >> 2;            // i-half (cols nh*128..+127)
    const int l31  = lane & 31;
    const int kh   = lane >> 5;          // selects b-pair {2kh, 2kh+1}

    const size_t OST = (size_t)BATCH * NOUT;

    // ---- reverse warm-up (scalar loads; ~14 MB chip-wide)
    const float* __restrict__ outW = outs + (size_t)(b0 + 2 * kh) * NOUT + mt * 32 + l31;
    float rtrA = 0.f, rtrB = 0.f;
    if (tc < NTC - 1) {
        for (int tb = t0 + TC + WARM; tb > t0 + TC; tb -= 8) {
            float vA[8], vB[8];
#pragma unroll
            for (int u = 0; u < 8; ++u) {
                vA[u] = outW[(size_t)(tb - 1 - u) * OST];
                vB[u] = outW[(size_t)(tb - 1 - u) * OST + NOUT];
            }
#pragma unroll
            for (int u = 0; u < 8; ++u) {
                rtrA = vA[u] + 0.5f * rtrA;
                rtrB = vB[u] + 0.5f * rtrB;
            }
        }
    }

    f32x16 acc[4];
#pragma unroll
    for (int j = 0; j < 4; ++j) acc[j] = (f32x16)(0.f);

    // ---- DMA decomposition (derived so LDS-linear == global-contiguous):
    // in stage 16 KiB = 16 x (t,b)-rows of 1 KiB; wave wv, instr r covers
    //   (q = 2r + (wv>>2), b = wv&3), lanes span i = lane*4..+3.
    // out stage 8 KiB = 8 pieces; wave wv covers (q = wv>>1,
    //   b = 2*(wv&1) + (lane>>5)), lanes span o = (lane&31)*4..+3.
    const float* inS  = in   + (size_t)(b0 + (wv & 3)) * NIN  + lane * 4;
    const float* outS = outs + (size_t)(b0 + 2 * (wv & 1) + kh) * NOUT + l31 * 4;
    const int    tin  = wv >> 2;         // + 2r
    const int    tot  = wv >> 1;
    char* inL  = inBase  + wv * 1024;
    char* outL = outBase + wv * 1024;

    auto dma_group = [&](int s, int g) {    // 3 DMA instrs / thread / group
        const int tg = t0 + g * G;
        gload16(inS  + (size_t)(tg + tin)     * (BATCH * NIN),  inL + s * 16384);
        gload16(inS  + (size_t)(tg + tin + 2) * (BATCH * NIN),  inL + s * 16384 + 8192);
        gload16(outS + (size_t)(tg + tot)     * (BATCH * NOUT), outL + s * 8192);
    };

    // LDS frag-read bases (byte offsets; s/q/be/tn fold into ds imm offsets).
    // B: byte = s*16384 + q*4096 + be*1024 + [kh*2048 + nh*512 + tn*128 + l31*4]
    // A: byte = s*8192  + q*2048 + be*512  + [kh*1024 + mt*128 + l31*4]
    const char* ilb = inBase  + kh * 2048 + nh * 512 + l31 * 4;
    const char* olb = outBase + kh * 1024 + mt * 128 + l31 * 4;

    auto body = [&](int s, int g, int vm) {
        // stage-s DMAs are the 3 oldest outstanding; up to 9 newer in flight
        if      (vm == 9) asm volatile("s_waitcnt vmcnt(9)" ::: "memory");
        else if (vm == 6) asm volatile("s_waitcnt vmcnt(6)" ::: "memory");
        else if (vm == 3) asm volatile("s_waitcnt vmcnt(3)" ::: "memory");
        else              asm volatile("s_waitcnt vmcnt(0)" ::: "memory");
        __builtin_amdgcn_s_barrier();            // all waves' stage-s data landed
        __builtin_amdgcn_sched_barrier(0);       // no ds_read hoists above

        // A side: read out-spike rows, reverse-scan rtrace (descending t)
        float vA[4], vB[4];
#pragma unroll
        for (int q = 0; q < 4; ++q) {
            vA[q] = *(const float*)(olb + s * 8192 + q * 2048);        // b = 2kh
            vB[q] = *(const float*)(olb + s * 8192 + q * 2048 + 512);  // b = 2kh+1
        }
        float aA[4], aB[4];
#pragma unroll
        for (int q = 3; q >= 0; --q) {
            rtrA = vA[q] + 0.5f * rtrA; aA[q] = rtrA;
            rtrB = vB[q] + 0.5f * rtrB; aB[q] = rtrB;
        }
        const bf16x8 a = frag_from4(pack_bf16(aA[0], aA[1]), pack_bf16(aA[2], aA[3]),
                                    pack_bf16(aB[0], aB[1]), pack_bf16(aB[2], aB[3]));
        bf16x8 bfr[4];
#pragma unroll
        for (int tn = 0; tn < 4; ++tn) {
            float p[8];
#pragma unroll
            for (int be = 0; be < 2; ++be)
#pragma unroll
                for (int q = 0; q < 4; ++q)
                    p[be * 4 + q] = *(const float*)
                        (ilb + s * 16384 + q * 4096 + be * 1024 + tn * 128);
            bfr[tn] = frag_from4(pack_bf16(p[0], p[1]), pack_bf16(p[2], p[3]),
                                 pack_bf16(p[4], p[5]), pack_bf16(p[6], p[7]));
        }
#pragma unroll
        for (int tn = 0; tn < 4; ++tn)
            acc[tn] = __builtin_amdgcn_mfma_f32_32x32x16_bf16(a, bfr[tn], acc[tn], 0, 0, 0);

        asm volatile("s_waitcnt lgkmcnt(0)" ::: "memory");  // my stage-s reads done
        __builtin_amdgcn_s_barrier();                       // everyone's reads done
        __builtin_amdgcn_sched_barrier(0);                  // DMA stays below barrier
        if (g >= 4) dma_group(s, g - 4);                    // refill stage s
    };

    // prologue: 12 DMAs outstanding (4 groups), then steady-state 4-deep
    dma_group(3, NG - 1);
    dma_group(2, NG - 2);
    dma_group(1, NG - 3);
    dma_group(0, NG - 4);
    for (int g = NG - 1; g >= 7; g -= 4) {
        body(3, g,     9);
        body(2, g - 1, 9);
        body(1, g - 2, 9);
        body(0, g - 3, 9);
    }
    body(3, 3, 9);   // outstanding 12 -> keep 9
    body(2, 2, 6);   // drain tail
    body(1, 1, 3);
    body(0, 0, 0);

    // ---- epilogue: D[row, col] -> dw[o = mt*32+row, i = (nh*4+j)*32+col] ----
    float* base = dst + (size_t)(use_atomic ? (blockIdx.x % nslots) : blockIdx.x) * OUT_ELEMS;
#pragma unroll
    for (int j = 0; j < 4; ++j) {
        const int icol = (nh * 4 + j) * 32 + l31;
#pragma unroll
        for (int r = 0; r < 16; ++r) {
            const int row = (r & 3) + 8 * (r >> 2) + 4 * kh;
            const int o   = mt * 32 + row;
            const float v = acc[j][r];
            if (use_atomic) atomicAdd(&base[o * NIN + icol], v);
            else            base[o * NIN + icol] = v;
        }
    }
}

__global__ void zero_kernel(float* p, int n) {
    int i = blockIdx.x * blockDim.x + threadIdx.x;
    if (i < n) p[i] = 0.f;
}

__global__ __launch_bounds__(256)
void reduce_kernel(const float* __restrict__ ws, float* __restrict__ outp, int nslots) {
    const int idx = blockIdx.x * 256 + threadIdx.x;
    float s = 0.f;
    int k = 0;
    for (; k + 16 <= nslots; k += 16) {
        float v[16];
#pragma unroll
        for (int u = 0; u < 16; ++u) v[u] = ws[(size_t)(k + u) * OUT_ELEMS + idx];
#pragma unroll
        for (int u = 0; u < 16; ++u) s += v[u];
    }
    for (; k < nslots; ++k) s += ws[(size_t)k * OUT_ELEMS + idx];
    outp[idx] = s;
}

extern "C" void kernel_launch(void* const* d_in, const int* in_sizes, int n_in,
                              void* d_out, int out_size, void* d_ws, size_t ws_size,
                              hipStream_t stream) {
    const float* in   = (const float*)d_in[0];
    const float* outs = (const float*)d_in[1];
    float* out = (float*)d_out;
    float* ws  = (float*)d_ws;

    const size_t slot_bytes = (size_t)OUT_ELEMS * sizeof(float);

    if (ws_size >= (size_t)NBLOCKS * slot_bytes) {
        // plain per-block partials + reduce (preferred; atomics cost ~+30 us, R4)
        stdp_main<<<NBLOCKS, 512, LDS_BYTES, stream>>>(in, outs, ws, NBLOCKS, 0);
        reduce_kernel<<<OUT_ELEMS / 256, 256, 0, stream>>>(ws, out, NBLOCKS);
    } else if (ws_size >= 16 * slot_bytes) {
        zero_kernel<<<(16 * OUT_ELEMS + 255) / 256, 256, 0, stream>>>(ws, 16 * OUT_ELEMS);
        stdp_main<<<NBLOCKS, 512, LDS_BYTES, stream>>>(in, outs, ws, 16, 1);
        reduce_kernel<<<OUT_ELEMS / 256, 256, 0, stream>>>(ws, out, 16);
    } else {
        zero_kernel<<<(OUT_ELEMS + 255) / 256, 256, 0, stream>>>(out, OUT_ELEMS);
        stdp_main<<<NBLOCKS, 512, LDS_BYTES, stream>>>(in, outs, out, 1, 1);
    }
}

// Round 9
// 443.629 us; speedup vs baseline: 1.0715x; 1.0167x over previous
//
#include <hip/hip_runtime.h>
#include <hip/hip_bf16.h>

// Problem constants (fixed by reference setup_inputs).
#define T_TOTAL 2048
#define BATCH   128
#define NIN     256
#define NOUT    128

// Reverse-scan formulation (see R3):
//   rtrace[t] = out[t] + 0.5*rtrace[t+1];  dw[o,i] = sum_{t,b} rtrace[t,b,o]*in[t,b,i]
//
// Evidence through R7: the global_load_lds path delivers ~5 B/cyc/CU no
// matter the depth (R5 d2 = R7 d4) or blocks/CU (R6 worse); warm-L3 replays
// are no faster (not DRAM-bound). R4 showed the plain-VGPR request path runs
// ~29 B/cyc/CU on this very kernel. => the two read paths are separate
// resources and we had everything on the slow one.
//
// ROUND 8/9 CHANGE (single variable vs R7): split streams across both paths.
//   in  (16 KiB/group, needs lane-redistribution) : stays HBM->LDS DMA, 4-deep.
//   out ( 8 KiB/group, consumed strictly per-lane) : direct per-lane VGPR
//        loads, 2-slot register double-buffer OA[2][8]; no LDS, no lgkm.
// Per slot: 8 scalar out-loads + 2 in-DMAs (issue order pinned o-then-d by
// sched_barrier). Steady manual wait = vmcnt(12): stage-s in-DMA completes
// with a 3-slot lead; out regs are additionally compiler-tracked. Tail waits
// 12/10/8/0; prologue slot 6. LDS: 4 stages x 16 KiB = 64 KiB (static).
// (R8 bench was an infra failure - container acquisition - resubmitting.)
#define TC      256                 // timesteps per block
#define BC      4                   // batches per block
#define WARM    32                  // reverse warm-up steps (0.5^32 ~ 2e-10)
#define G       4                   // timesteps per MFMA K-group (K = G*BC = 16)
#define NTC     (T_TOTAL / TC)      // 8
#define NBC     (BATCH / BC)        // 32
#define NBLOCKS (NTC * NBC)         // 256  (1 block/CU)
#define NG      (TC / G)            // 64 K-groups per block

#define OUT_ELEMS (NOUT * NIN)      // 32768

static_assert(NG % 4 == 0, "4-stage pipeline needs NG % 4 == 0");

typedef __attribute__((ext_vector_type(8)))  __bf16 bf16x8;
typedef __attribute__((ext_vector_type(2)))  __bf16 bf16x2;
typedef __attribute__((ext_vector_type(16))) float  f32x16;

// packed f32x2 -> bf16x2 (v_cvt_pk_bf16_f32 on gfx950, RTNE; exact for {0,1})
static __device__ __forceinline__ unsigned pack_bf16(float a, float b) {
    bf16x2 v = { (__bf16)a, (__bf16)b };
    union { bf16x2 v; unsigned u; } c; c.v = v; return c.u;
}

static __device__ __forceinline__ bf16x8 frag_from4(unsigned d0, unsigned d1,
                                                    unsigned d2, unsigned d3) {
    union { unsigned u[4]; bf16x8 v; } c;
    c.u[0] = d0; c.u[1] = d1; c.u[2] = d2; c.u[3] = d3; return c.v;
}

// Direct global->LDS DMA, 16 B/lane. LDS dest = wave-uniform base + lane*16
// (m104); size must be a literal.
static __device__ __forceinline__ void gload16(const float* g, void* l) {
    __builtin_amdgcn_global_load_lds(
        (const __attribute__((address_space(1))) void*)g,
        (__attribute__((address_space(3))) void*)l,
        16, 0, 0);
}

static __device__ __forceinline__ void wait_vm(int N) {
    if      (N == 12) asm volatile("s_waitcnt vmcnt(12)" ::: "memory");
    else if (N == 10) asm volatile("s_waitcnt vmcnt(10)" ::: "memory");
    else if (N == 8)  asm volatile("s_waitcnt vmcnt(8)"  ::: "memory");
    else if (N == 6)  asm volatile("s_waitcnt vmcnt(6)"  ::: "memory");
    else              asm volatile("s_waitcnt vmcnt(0)"  ::: "memory");
}

// Wave w = (mt = w&3, nh = w>>2): output tile o in [mt*32,+32), i in
// [nh*128,+128). Lane (l31, kh): A-frag elem j: (q=j&3, b=2kh+(j>=4)) ->
// lane scans rtrace for (o=mt*32+l31, b0+2kh / b0+2kh+1) in registers,
// sourcing out-spikes from its OWN scalar loads (no redistribution needed).
// B-frag elem j, tile tn: in[tg+(j&3)][b0+2kh+(j>=4)][(nh*4+tn)*32+l31],
// sourced from the LDS stage filled by DMA.
__global__ __launch_bounds__(512, 2)
void stdp_main(const float* __restrict__ in, const float* __restrict__ outs,
               float* __restrict__ dst, int nslots, int use_atomic)
{
    // in staging only: 4 stages x [q(4)][b(4)][i(256)] fp32 = 64 KiB, linear.
    __shared__ float in_lds[4][G * BC * NIN];

    const int tid = threadIdx.x;
    const int bc  = blockIdx.x % NBC;
    const int tc  = blockIdx.x / NBC;
    const int b0  = bc * BC;
    const int t0  = tc * TC;

    const int lane = tid & 63;
    const int wv   = tid >> 6;           // 8 waves
    const int mt   = wv & 3;             // o-tile (rows mt*32..+31)
    const int nh   = wv >> 2;            // i-half (cols nh*128..+127)
    const int l31  = lane & 31;
    const int kh   = lane >> 5;          // selects b-pair {2kh, 2kh+1}

    const size_t OST = (size_t)BATCH * NOUT;
    const float* __restrict__ outW = outs + (size_t)(b0 + 2 * kh) * NOUT + mt * 32 + l31;

    float rtrA = 0.f, rtrB = 0.f;

    // ---- reverse warm-up (scalar loads; compiler-tracked waits complete
    //      before the pipeline starts, so manual vmcnt counts stay exact)
    if (tc < NTC - 1) {
        for (int tb = t0 + TC + WARM; tb > t0 + TC; tb -= 8) {
            float vA[8], vB[8];
#pragma unroll
            for (int u = 0; u < 8; ++u) {
                vA[u] = outW[(size_t)(tb - 1 - u) * OST];
                vB[u] = outW[(size_t)(tb - 1 - u) * OST + NOUT];
            }
#pragma unroll
            for (int u = 0; u < 8; ++u) {
                rtrA = vA[u] + 0.5f * rtrA;
                rtrB = vB[u] + 0.5f * rtrB;
            }
        }
    }

    f32x16 acc[4];
#pragma unroll
    for (int j = 0; j < 4; ++j) acc[j] = (f32x16)(0.f);

    // ---- in DMA decomposition (LDS-linear == global-contiguous):
    // stage 16 KiB = 16 x (t,b)-rows of 1 KiB; wave wv, instr r covers
    // (q = (wv>>2) + 2r, b = wv&3), lanes span i = lane*4..+3.
    const float* inS = in + (size_t)(b0 + (wv & 3)) * NIN + lane * 4;
    const int    tin = wv >> 2;
    char* inL = (char*)&in_lds[0][0] + wv * 1024;

    auto dma_in = [&](int s, int g) {       // 2 DMA instrs / thread / group
        const int tg = t0 + g * G;
        gload16(inS + (size_t)(tg + tin)     * (BATCH * NIN), inL + s * 16384);
        gload16(inS + (size_t)(tg + tin + 2) * (BATCH * NIN), inL + s * 16384 + 8192);
    };

    // out register double-buffer: A[q] = out[tg+q][b0+2kh][o], A[4+q] = b+1.
    float OA0[8], OA1[8];
    auto oload = [&](float (&A)[8], int g) {   // 8 scalar loads / thread
        const int tg = t0 + g * G;
#pragma unroll
        for (int q = 0; q < 4; ++q) {
            A[q]     = outW[(size_t)(tg + q) * OST];
            A[4 + q] = outW[(size_t)(tg + q) * OST + NOUT];
        }
    };

    // B-frag LDS read base:
    // byte = s*16384 + q*4096 + be*1024 + [kh*2048 + nh*512 + tn*128 + l31*4]
    const char* ilb = (const char*)&in_lds[0][0] + kh * 2048 + nh * 512 + l31 * 4;

    auto body = [&](int s, const float (&A)[8], int N) {
        wait_vm(N);                              // stage-s DMAs landed
        __builtin_amdgcn_s_barrier();
        __builtin_amdgcn_sched_barrier(0);       // no ds_read hoists above

        // A side: reverse-scan rtrace from registers (descending t)
        float aA[4], aB[4];
#pragma unroll
        for (int q = 3; q >= 0; --q) {
            rtrA = A[q]     + 0.5f * rtrA; aA[q] = rtrA;
            rtrB = A[4 + q] + 0.5f * rtrB; aB[q] = rtrB;
        }
        const bf16x8 a = frag_from4(pack_bf16(aA[0], aA[1]), pack_bf16(aA[2], aA[3]),
                                    pack_bf16(aB[0], aB[1]), pack_bf16(aB[2], aB[3]));
        bf16x8 bfr[4];
#pragma unroll
        for (int tn = 0; tn < 4; ++tn) {
            float p[8];
#pragma unroll
            for (int be = 0; be < 2; ++be)
#pragma unroll
                for (int q = 0; q < 4; ++q)
                    p[be * 4 + q] = *(const float*)
                        (ilb + s * 16384 + q * 4096 + be * 1024 + tn * 128);
            bfr[tn] = frag_from4(pack_bf16(p[0], p[1]), pack_bf16(p[2], p[3]),
                                 pack_bf16(p[4], p[5]), pack_bf16(p[6], p[7]));
        }
#pragma unroll
        for (int tn = 0; tn < 4; ++tn)
            acc[tn] = __builtin_amdgcn_mfma_f32_32x32x16_bf16(a, bfr[tn], acc[tn], 0, 0, 0);

        asm volatile("s_waitcnt lgkmcnt(0)" ::: "memory");  // my stage-s reads done
        __builtin_amdgcn_s_barrier();                       // everyone's reads done
        __builtin_amdgcn_sched_barrier(0);                  // issues stay below
    };

    // SLOT g (descending): consume stage s=g&3 from bank parity(g); then issue
    // out-loads for slot g-2 (same bank) and the stage-s refill DMA for g-4.
#define SLOT(S, GG, BANK, N)                                   \
    do {                                                       \
        body(S, BANK, N);                                      \
        if ((GG) >= 2) oload(BANK, (GG) - 2);                  \
        __builtin_amdgcn_sched_barrier(0);                     \
        if ((GG) >= 4) dma_in(S, (GG) - 4);                    \
        __builtin_amdgcn_sched_barrier(0);                     \
    } while (0)

    // prologue: o(63)->OA1, o(62)->OA0, then 4 stages of in-DMA (8 instrs)
    oload(OA1, NG - 1);
    oload(OA0, NG - 2);
    __builtin_amdgcn_sched_barrier(0);
    dma_in(3, NG - 1);
    dma_in(2, NG - 2);
    dma_in(1, NG - 3);
    dma_in(0, NG - 4);
    __builtin_amdgcn_sched_barrier(0);

    SLOT(3, NG - 1, OA1, 6);     // younger(d(63)) = 6 at this point
    SLOT(2, NG - 2, OA0, 12);
    SLOT(1, NG - 3, OA1, 12);
    SLOT(0, NG - 4, OA0, 12);
    for (int gg = NG - 5; gg >= 7; gg -= 4) {   // gg odd -> parity 1 first
        SLOT(3, gg,     OA1, 12);
        SLOT(2, gg - 1, OA0, 12);
        SLOT(1, gg - 2, OA1, 12);
        SLOT(0, gg - 3, OA0, 12);
    }
    SLOT(3, 3, OA1, 12);
    SLOT(2, 2, OA0, 10);
    SLOT(1, 1, OA1, 8);
    SLOT(0, 0, OA0, 0);          // final slot drains everything
#undef SLOT

    // ---- epilogue: D[row, col] -> dw[o = mt*32+row, i = (nh*4+j)*32+col] ----
    float* base = dst + (size_t)(use_atomic ? (blockIdx.x % nslots) : blockIdx.x) * OUT_ELEMS;
#pragma unroll
    for (int j = 0; j < 4; ++j) {
        const int icol = (nh * 4 + j) * 32 + l31;
#pragma unroll
        for (int r = 0; r < 16; ++r) {
            const int row = (r & 3) + 8 * (r >> 2) + 4 * kh;
            const int o   = mt * 32 + row;
            const float v = acc[j][r];
            if (use_atomic) atomicAdd(&base[o * NIN + icol], v);
            else            base[o * NIN + icol] = v;
        }
    }
}

__global__ void zero_kernel(float* p, int n) {
    int i = blockIdx.x * blockDim.x + threadIdx.x;
    if (i < n) p[i] = 0.f;
}

__global__ __launch_bounds__(256)
void reduce_kernel(const float* __restrict__ ws, float* __restrict__ outp, int nslots) {
    const int idx = blockIdx.x * 256 + threadIdx.x;
    float s = 0.f;
    int k = 0;
    for (; k + 16 <= nslots; k += 16) {
        float v[16];
#pragma unroll
        for (int u = 0; u < 16; ++u) v[u] = ws[(size_t)(k + u) * OUT_ELEMS + idx];
#pragma unroll
        for (int u = 0; u < 16; ++u) s += v[u];
    }
    for (; k < nslots; ++k) s += ws[(size_t)k * OUT_ELEMS + idx];
    outp[idx] = s;
}

extern "C" void kernel_launch(void* const* d_in, const int* in_sizes, int n_in,
                              void* d_out, int out_size, void* d_ws, size_t ws_size,
                              hipStream_t stream) {
    const float* in   = (const float*)d_in[0];
    const float* outs = (const float*)d_in[1];
    float* out = (float*)d_out;
    float* ws  = (float*)d_ws;

    const size_t slot_bytes = (size_t)OUT_ELEMS * sizeof(float);

    if (ws_size >= (size_t)NBLOCKS * slot_bytes) {
        // plain per-block partials + reduce (preferred; atomics cost ~+30 us, R4)
        stdp_main<<<NBLOCKS, 512, 0, stream>>>(in, outs, ws, NBLOCKS, 0);
        reduce_kernel<<<OUT_ELEMS / 256, 256, 0, stream>>>(ws, out, NBLOCKS);
    } else if (ws_size >= 16 * slot_bytes) {
        zero_kernel<<<(16 * OUT_ELEMS + 255) / 256, 256, 0, stream>>>(ws, 16 * OUT_ELEMS);
        stdp_main<<<NBLOCKS, 512, 0, stream>>>(in, outs, ws, 16, 1);
        reduce_kernel<<<OUT_ELEMS / 256, 256, 0, stream>>>(ws, out, 16);
    } else {
        zero_kernel<<<(OUT_ELEMS + 255) / 256, 256, 0, stream>>>(out, OUT_ELEMS);
        stdp_main<<<NBLOCKS, 512, 0, stream>>>(in, outs, out, 1, 1);
    }
}